// Round 1
// baseline (275.287 us; speedup 1.0000x reference)
//
#include <hip/hip_runtime.h>
#include <hip/hip_bf16.h>

using bf16 = __hip_bfloat16;
typedef __bf16 bf16x8_t __attribute__((ext_vector_type(8)));
typedef float f32x4_t __attribute__((ext_vector_type(4)));

// ---------------------------------------------------------------- helpers
__device__ __forceinline__ void gl16(bf16* l, const bf16* g) {
  // async global->LDS, 16B per lane; LDS dest must be linear (base + lane*16)
  __builtin_amdgcn_global_load_lds(
      (const __attribute__((address_space(1))) unsigned int*)g,
      (__attribute__((address_space(3))) unsigned int*)l, 16, 0, 0);
}

// ---------------------------------------------------------------- f32 -> bf16 convert (vectorized)
__global__ __launch_bounds__(256) void cvt_f32_bf16(const float* __restrict__ in,
                                                    bf16* __restrict__ out, int n4) {
  int i = blockIdx.x * 256 + threadIdx.x;
  if (i >= n4) return;
  float4 v = ((const float4*)in)[i];
  union { ushort4 u; bf16 b[4]; } o;
  o.b[0] = __float2bfloat16(v.x);
  o.b[1] = __float2bfloat16(v.y);
  o.b[2] = __float2bfloat16(v.z);
  o.b[3] = __float2bfloat16(v.w);
  ((ushort4*)out)[i] = o.u;
}

// ---------------------------------------------------------------- transpose + convert: in[R][C] f32 -> out[C][R] bf16
__global__ __launch_bounds__(256) void transpose_cvt(const float* __restrict__ in,
                                                     bf16* __restrict__ out, int R, int C) {
  __shared__ float t[32][33];
  int bx = blockIdx.x * 32, by = blockIdx.y * 32;
  int tx = threadIdx.x & 31, ty = threadIdx.x >> 5;  // ty 0..7
#pragma unroll
  for (int r = 0; r < 32; r += 8)
    t[ty + r][tx] = in[(size_t)(by + ty + r) * C + bx + tx];
  __syncthreads();
#pragma unroll
  for (int r = 0; r < 32; r += 8)
    out[(size_t)(bx + ty + r) * R + by + tx] = __float2bfloat16(t[tx][ty + r]);
}

// ---------------------------------------------------------------- 128x128 bf16 MFMA GEMM (m97 structure)
// C[M,N] = A[M,K] @ Bt[N,K]^T + bias[N].  OUT_BF16: 1 -> bf16 C, 0 -> f32 C.
template <int OUT_BF16>
__global__ __launch_bounds__(256, 2) void gemm_bt(const bf16* __restrict__ A,
                                                  const bf16* __restrict__ Bt,
                                                  const float* __restrict__ bias,
                                                  void* __restrict__ Cv,
                                                  int M, int N, int K) {
  __shared__ __align__(16) bf16 As[128 * 32];
  __shared__ __align__(16) bf16 Bs[128 * 32];
  const int tid = threadIdx.x;
  const int m0 = blockIdx.y * 128, n0 = blockIdx.x * 128;
  const int w = tid >> 6, lane = tid & 63;
  const int wr = w >> 1, wc = w & 1;
  const int lr = lane & 15, lk = (lane >> 4) << 3;

  // staging: each thread owns two 16B chunks of A and B per K-step
  const int srow = tid >> 2;           // 0..63
  const int scol = (tid & 3) << 3;     // 0,8,16,24 (bf16 elems)
  const bf16* ga0 = A + (size_t)(m0 + srow) * K + scol;
  const bf16* ga1 = A + (size_t)(m0 + srow + 64) * K + scol;
  const bf16* gb0 = Bt + (size_t)(n0 + srow) * K + scol;
  const bf16* gb1 = Bt + (size_t)(n0 + srow + 64) * K + scol;
  bf16* la0 = As + tid * 8;
  bf16* la1 = As + (tid + 256) * 8;
  bf16* lb0 = Bs + tid * 8;
  bf16* lb1 = Bs + (tid + 256) * 8;

  f32x4_t acc[4][4] = {};

  for (int k0 = 0; k0 < K; k0 += 32) {
    gl16(la0, ga0); gl16(la1, ga1);
    gl16(lb0, gb0); gl16(lb1, gb1);
    ga0 += 32; ga1 += 32; gb0 += 32; gb1 += 32;
    __syncthreads();  // compiler drains vmcnt before s_barrier

    bf16x8_t af[4], bfv[4];
#pragma unroll
    for (int m = 0; m < 4; ++m)
      af[m] = *(const bf16x8_t*)(As + ((wr * 64 + m * 16 + lr) * 32 + lk));
#pragma unroll
    for (int n = 0; n < 4; ++n)
      bfv[n] = *(const bf16x8_t*)(Bs + ((wc * 64 + n * 16 + lr) * 32 + lk));
#pragma unroll
    for (int m = 0; m < 4; ++m)
#pragma unroll
      for (int n = 0; n < 4; ++n)
        acc[m][n] = __builtin_amdgcn_mfma_f32_16x16x32_bf16(af[m], bfv[n], acc[m][n], 0, 0, 0);
    __syncthreads();
  }

  // epilogue: D layout col=lane&15, row=(lane>>4)*4+j   [m89-verified]
  const int r0 = (lane >> 4) << 2;
#pragma unroll
  for (int m = 0; m < 4; ++m) {
    int row = m0 + wr * 64 + m * 16 + r0;
#pragma unroll
    for (int n = 0; n < 4; ++n) {
      int col = n0 + wc * 64 + n * 16 + lr;
      float bv = bias[col];
#pragma unroll
      for (int j = 0; j < 4; ++j) {
        float v = acc[m][n][j] + bv;
        if (OUT_BF16)
          ((bf16*)Cv)[(size_t)(row + j) * N + col] = __float2bfloat16(v);
        else
          ((float*)Cv)[(size_t)(row + j) * N + col] = v;
      }
    }
  }
}

// ---------------------------------------------------------------- per-token head-mixing attention
// qkv[t][0:1024]=q, [1024:2048]=k, [2048:3072]=v ; heads: idx = h*64+d
// logits[qh][kh] = 0.125 * dot(q[qh], k[kh]); softmax over kh; out[qh][d] = sum_kh p*v[kh][d]
#define HPAD 65
__global__ __launch_bounds__(256) void attn_tok(const bf16* __restrict__ qkv,
                                                bf16* __restrict__ out) {
  __shared__ float sm[4 * (3 * 16 * HPAD + 16 * 17)];
  const int w = threadIdx.x >> 6, l = threadIdx.x & 63;
  const int t = blockIdx.x * 4 + w;
  float* q_s = sm + w * (3 * 16 * HPAD + 16 * 17);
  float* k_s = q_s + 16 * HPAD;
  float* v_s = k_s + 16 * HPAD;
  float* a_s = v_s + 16 * HPAD;

  const bf16* base = qkv + (size_t)t * 3072;
  // load 3072 bf16 (48/lane) -> f32 LDS with +1 padded rows
#pragma unroll
  for (int c = 0; c < 6; ++c) {
    int g = c * 512 + l * 8;
    bf16x8_t d = *(const bf16x8_t*)(base + g);
    int region = g >> 10;            // 0=q 1=k 2=v
    int hh = (g & 1023) >> 6, dd = g & 63;
    float* dst = q_s + region * 16 * HPAD + hh * HPAD + dd;
#pragma unroll
    for (int j = 0; j < 8; ++j) dst[j] = (float)d[j];
  }
  __syncthreads();

  // logits + softmax: lane computes rows qh = 4j + (l>>4), col kh = l&15
  const int kh = l & 15, lg4 = l >> 4;
#pragma unroll
  for (int j = 0; j < 4; ++j) {
    int qh = 4 * j + lg4;
    const float* qp = q_s + qh * HPAD;
    const float* kp = k_s + kh * HPAD;
    float s = 0.f;
#pragma unroll
    for (int d = 0; d < 64; ++d) s += qp[d] * kp[d];
    s *= 0.125f;
    float mx = s;
#pragma unroll
    for (int off = 8; off; off >>= 1) mx = fmaxf(mx, __shfl_xor(mx, off, 16));
    float e = __expf(s - mx);
    float sum = e;
#pragma unroll
    for (int off = 8; off; off >>= 1) sum += __shfl_xor(sum, off, 16);
    a_s[qh * 17 + kh] = e / sum;
  }
  __syncthreads();

  // PV: lane owns d = l
  float vv[16];
#pragma unroll
  for (int k2 = 0; k2 < 16; ++k2) vv[k2] = v_s[k2 * HPAD + l];
  bf16* ob = out + (size_t)t * 1024 + l;
#pragma unroll
  for (int qh = 0; qh < 16; ++qh) {
    float o = 0.f;
#pragma unroll
    for (int k2 = 0; k2 < 16; ++k2) o += a_s[qh * 17 + k2] * vv[k2];
    ob[qh * 64] = __float2bfloat16(o);
  }
}

// ---------------------------------------------------------------- launch
extern "C" void kernel_launch(void* const* d_in, const int* in_sizes, int n_in,
                              void* d_out, int out_size, void* d_ws, size_t ws_size,
                              hipStream_t stream) {
  const float* x    = (const float*)d_in[0];  // [16384,1024]
  const float* Wqkv = (const float*)d_in[1];  // [1024,3072]
  const float* bqkv = (const float*)d_in[2];  // [3072]
  const float* Wout = (const float*)d_in[3];  // [1024,1024]
  const float* bout = (const float*)d_in[4];  // [1024]
  float* y = (float*)d_out;                   // [16384,1024]

  const int T = 16384, HD = 1024, N1 = 3072;

  // workspace layout (xb aliases attn_out: xb dead after GEMM1, ao written after)
  char* ws = (char*)d_ws;
  size_t off = 0;
  bf16* xb  = (bf16*)(ws + off); off += (size_t)T * HD * 2;        // 33.55 MB (also = attn_out)
  bf16* w1t = (bf16*)(ws + off); off += (size_t)N1 * HD * 2;       //  6.29 MB
  bf16* w2t = (bf16*)(ws + off); off += (size_t)HD * HD * 2;       //  2.10 MB
  bf16* qkv = (bf16*)(ws + off); off += (size_t)T * N1 * 2;        // 100.66 MB
  if (ws_size < off) return;  // insufficient scratch — fail visibly
  bf16* ao = xb;

  cvt_f32_bf16<<<(T * HD / 4 + 255) / 256, 256, 0, stream>>>(x, xb, T * HD / 4);
  transpose_cvt<<<dim3(N1 / 32, HD / 32), 256, 0, stream>>>(Wqkv, w1t, HD, N1);
  transpose_cvt<<<dim3(HD / 32, HD / 32), 256, 0, stream>>>(Wout, w2t, HD, HD);

  gemm_bt<1><<<dim3(N1 / 128, T / 128), 256, 0, stream>>>(xb, w1t, bqkv, qkv, T, N1, HD);
  attn_tok<<<T / 4, 256, 0, stream>>>(qkv, ao);
  gemm_bt<0><<<dim3(HD / 128, T / 128), 256, 0, stream>>>(ao, w2t, bout, y, T, HD, HD);
}

// Round 2
// 232.231 us; speedup vs baseline: 1.1854x; 1.1854x over previous
//
#include <hip/hip_runtime.h>
#include <hip/hip_bf16.h>

using bf16 = __hip_bfloat16;
typedef __bf16 bf16x8_t __attribute__((ext_vector_type(8)));
typedef float f32x4_t __attribute__((ext_vector_type(4)));

// ---------------------------------------------------------------- helpers
__device__ __forceinline__ void gl16(bf16* l, const bf16* g) {
  // async global->LDS, 16B per lane; LDS dest must be linear (base + lane*16)
  __builtin_amdgcn_global_load_lds(
      (const __attribute__((address_space(1))) unsigned int*)g,
      (__attribute__((address_space(3))) unsigned int*)l, 16, 0, 0);
}

// ---------------------------------------------------------------- f32 -> bf16 convert (vectorized)
__global__ __launch_bounds__(256) void cvt_f32_bf16(const float* __restrict__ in,
                                                    bf16* __restrict__ out, int n4) {
  int i = blockIdx.x * 256 + threadIdx.x;
  if (i >= n4) return;
  float4 v = ((const float4*)in)[i];
  union { ushort4 u; bf16 b[4]; } o;
  o.b[0] = __float2bfloat16(v.x);
  o.b[1] = __float2bfloat16(v.y);
  o.b[2] = __float2bfloat16(v.z);
  o.b[3] = __float2bfloat16(v.w);
  ((ushort4*)out)[i] = o.u;
}

// ---------------------------------------------------------------- transpose + convert: in[R][C] f32 -> out[C][R] bf16
__global__ __launch_bounds__(256) void transpose_cvt(const float* __restrict__ in,
                                                     bf16* __restrict__ out, int R, int C) {
  __shared__ float t[32][33];
  int bx = blockIdx.x * 32, by = blockIdx.y * 32;
  int tx = threadIdx.x & 31, ty = threadIdx.x >> 5;  // ty 0..7
#pragma unroll
  for (int r = 0; r < 32; r += 8)
    t[ty + r][tx] = in[(size_t)(by + ty + r) * C + bx + tx];
  __syncthreads();
#pragma unroll
  for (int r = 0; r < 32; r += 8)
    out[(size_t)(bx + ty + r) * R + by + tx] = __float2bfloat16(t[tx][ty + r]);
}

// ---------------------------------------------------------------- 128x128 bf16 MFMA GEMM (m97 structure)
// C[M,N] = A[M,K] @ Bt[N,K]^T + bias[N].  OUT_BF16: 1 -> bf16 C, 0 -> f32 C.
template <int OUT_BF16>
__global__ __launch_bounds__(256, 2) void gemm_bt(const bf16* __restrict__ A,
                                                  const bf16* __restrict__ Bt,
                                                  const float* __restrict__ bias,
                                                  void* __restrict__ Cv,
                                                  int M, int N, int K) {
  __shared__ __align__(16) bf16 As[128 * 32];
  __shared__ __align__(16) bf16 Bs[128 * 32];
  const int tid = threadIdx.x;
  const int m0 = blockIdx.y * 128, n0 = blockIdx.x * 128;
  const int w = tid >> 6, lane = tid & 63;
  const int wr = w >> 1, wc = w & 1;
  const int lr = lane & 15, lk = (lane >> 4) << 3;

  const int srow = tid >> 2;           // 0..63
  const int scol = (tid & 3) << 3;     // 0,8,16,24 (bf16 elems)
  const bf16* ga0 = A + (size_t)(m0 + srow) * K + scol;
  const bf16* ga1 = A + (size_t)(m0 + srow + 64) * K + scol;
  const bf16* gb0 = Bt + (size_t)(n0 + srow) * K + scol;
  const bf16* gb1 = Bt + (size_t)(n0 + srow + 64) * K + scol;
  bf16* la0 = As + tid * 8;
  bf16* la1 = As + (tid + 256) * 8;
  bf16* lb0 = Bs + tid * 8;
  bf16* lb1 = Bs + (tid + 256) * 8;

  f32x4_t acc[4][4] = {};

  for (int k0 = 0; k0 < K; k0 += 32) {
    gl16(la0, ga0); gl16(la1, ga1);
    gl16(lb0, gb0); gl16(lb1, gb1);
    ga0 += 32; ga1 += 32; gb0 += 32; gb1 += 32;
    __syncthreads();

    bf16x8_t af[4], bfv[4];
#pragma unroll
    for (int m = 0; m < 4; ++m)
      af[m] = *(const bf16x8_t*)(As + ((wr * 64 + m * 16 + lr) * 32 + lk));
#pragma unroll
    for (int n = 0; n < 4; ++n)
      bfv[n] = *(const bf16x8_t*)(Bs + ((wc * 64 + n * 16 + lr) * 32 + lk));
#pragma unroll
    for (int m = 0; m < 4; ++m)
#pragma unroll
      for (int n = 0; n < 4; ++n)
        acc[m][n] = __builtin_amdgcn_mfma_f32_16x16x32_bf16(af[m], bfv[n], acc[m][n], 0, 0, 0);
    __syncthreads();
  }

  const int r0 = (lane >> 4) << 2;
#pragma unroll
  for (int m = 0; m < 4; ++m) {
    int row = m0 + wr * 64 + m * 16 + r0;
#pragma unroll
    for (int n = 0; n < 4; ++n) {
      int col = n0 + wc * 64 + n * 16 + lr;
      float bv = bias[col];
#pragma unroll
      for (int j = 0; j < 4; ++j) {
        float v = acc[m][n][j] + bv;
        if (OUT_BF16)
          ((bf16*)Cv)[(size_t)(row + j) * N + col] = __float2bfloat16(v);
        else
          ((float*)Cv)[(size_t)(row + j) * N + col] = v;
      }
    }
  }
}

// ---------------------------------------------------------------- per-token head-mixing attention (MFMA)
// qkv[t][0:1024]=q, [1024:2048]=k, [2048:3072]=v ; head layout idx = h*64+d
// logits[qh][kh] = 0.125 * dot(q[qh], k[kh]); softmax over kh; out[qh][d] = sum_kh p*v[kh][d]
// One wave per token. QK^T: 2x mfma_16x16x32 with fragments loaded straight from global.
// PV: 4x mfma_16x16x32 (K padded 32; upper half zeroed), P transposed through tiny LDS.
#define PSTR 48  // P row stride in bf16 (96 B: 16B-aligned rows, spreads banks)
__global__ __launch_bounds__(256) void attn_tok(const bf16* __restrict__ qkv,
                                                bf16* __restrict__ out) {
  __shared__ __align__(16) bf16 vs[4][1024];
  __shared__ __align__(16) bf16 ps[4][16 * PSTR];
  const int w = threadIdx.x >> 6, l = threadIdx.x & 63;
  const int t = blockIdx.x * 4 + w;
  const int lr = l & 15, lg = l >> 4;
  const bf16* base = qkv + (size_t)t * 3072;

  // stage v (16x64 bf16) linearly into LDS: lane l covers elems [l*16, l*16+16)
  bf16x8_t v0 = *(const bf16x8_t*)(base + 2048 + l * 16);
  bf16x8_t v1 = *(const bf16x8_t*)(base + 2048 + l * 16 + 8);
  *(bf16x8_t*)(&vs[w][l * 16]) = v0;
  *(bf16x8_t*)(&vs[w][l * 16 + 8]) = v1;

  // zero P pad: rows l>>2, cols 16+(l&3)*4 .. +4  (covers cols 16..31 of all 16 rows)
  *(unsigned long long*)(&ps[w][(l >> 2) * PSTR + 16 + (l & 3) * 4]) = 0ULL;

  // ---- QK^T: C[qh][kh] = sum_d q[qh][d]*k[kh][d]
  const bf16* qp = base + lr * 64 + lg * 8;
  const bf16* kp = base + 1024 + lr * 64 + lg * 8;
  bf16x8_t qa0 = *(const bf16x8_t*)qp;
  bf16x8_t ka0 = *(const bf16x8_t*)kp;
  bf16x8_t qa1 = *(const bf16x8_t*)(qp + 32);
  bf16x8_t ka1 = *(const bf16x8_t*)(kp + 32);
  f32x4_t s = {};
  s = __builtin_amdgcn_mfma_f32_16x16x32_bf16(qa0, ka0, s, 0, 0, 0);
  s = __builtin_amdgcn_mfma_f32_16x16x32_bf16(qa1, ka1, s, 0, 0, 0);
  // lane holds s[j] = logits[qh=lg*4+j][kh=lr]

  // ---- softmax over kh (= across the 16 lanes of each 16-lane group)
#pragma unroll
  for (int j = 0; j < 4; ++j) {
    float x = s[j] * 0.125f;
    float mx = x;
#pragma unroll
    for (int off = 8; off; off >>= 1) mx = fmaxf(mx, __shfl_xor(mx, off, 16));
    float e = __expf(x - mx);
    float sum = e;
#pragma unroll
    for (int off = 8; off; off >>= 1) sum += __shfl_xor(sum, off, 16);
    ps[w][(lg * 4 + j) * PSTR + lr] = __float2bfloat16(e / sum);  // P[qh][kh]
  }

  // ---- PV: out[qh][d] = sum_kh P[qh][kh] * V[kh][d], K padded to 32 (zeros)
  // A-frag: P[lr][lg*8+j]  (16B-aligned contiguous read; cols>=16 are the zero pad)
  bf16x8_t pf = *(const bf16x8_t*)(&ps[w][lr * PSTR + lg * 8]);
  bf16x8_t vf[4] = {};  // B-frag per d-chunk: Bt[d0+lr][kh=lg*8+j] = V[kh][d0+lr]
  if (l < 32) {         // kh = lg*8+j < 16 only for lanes 0..31; others stay zero
#pragma unroll
    for (int c = 0; c < 4; ++c)
#pragma unroll
      for (int j = 0; j < 8; ++j)
        vf[c][j] = (__bf16)vs[w][(lg * 8 + j) * 64 + c * 16 + lr];
  }
  f32x4_t o[4] = {};
#pragma unroll
  for (int c = 0; c < 4; ++c)
    o[c] = __builtin_amdgcn_mfma_f32_16x16x32_bf16(pf, vf[c], o[c], 0, 0, 0);

  // ---- store: lane l -> out[t][ (lg*4+j)*64 + c*16 + lr ]
  bf16* ob = out + (size_t)t * 1024;
#pragma unroll
  for (int c = 0; c < 4; ++c)
#pragma unroll
    for (int j = 0; j < 4; ++j)
      ob[(lg * 4 + j) * 64 + c * 16 + lr] = __float2bfloat16(o[c][j]);
}

// ---------------------------------------------------------------- launch
extern "C" void kernel_launch(void* const* d_in, const int* in_sizes, int n_in,
                              void* d_out, int out_size, void* d_ws, size_t ws_size,
                              hipStream_t stream) {
  const float* x    = (const float*)d_in[0];  // [16384,1024]
  const float* Wqkv = (const float*)d_in[1];  // [1024,3072]
  const float* bqkv = (const float*)d_in[2];  // [3072]
  const float* Wout = (const float*)d_in[3];  // [1024,1024]
  const float* bout = (const float*)d_in[4];  // [1024]
  float* y = (float*)d_out;                   // [16384,1024]

  const int T = 16384, HD = 1024, N1 = 3072;

  char* ws = (char*)d_ws;
  size_t off = 0;
  bf16* xb  = (bf16*)(ws + off); off += (size_t)T * HD * 2;        // 33.55 MB (also = attn_out)
  bf16* w1t = (bf16*)(ws + off); off += (size_t)N1 * HD * 2;       //  6.29 MB
  bf16* w2t = (bf16*)(ws + off); off += (size_t)HD * HD * 2;       //  2.10 MB
  bf16* qkv = (bf16*)(ws + off); off += (size_t)T * N1 * 2;        // 100.66 MB
  if (ws_size < off) return;
  bf16* ao = xb;  // xb dead after GEMM1; reuse as attention output

  cvt_f32_bf16<<<(T * HD / 4 + 255) / 256, 256, 0, stream>>>(x, xb, T * HD / 4);
  transpose_cvt<<<dim3(N1 / 32, HD / 32), 256, 0, stream>>>(Wqkv, w1t, HD, N1);
  transpose_cvt<<<dim3(HD / 32, HD / 32), 256, 0, stream>>>(Wout, w2t, HD, HD);

  gemm_bt<1><<<dim3(N1 / 128, T / 128), 256, 0, stream>>>(xb, w1t, bqkv, qkv, T, N1, HD);
  attn_tok<<<T / 4, 256, 0, stream>>>(qkv, ao);
  gemm_bt<0><<<dim3(HD / 128, T / 128), 256, 0, stream>>>(ao, w2t, bout, y, T, HD, HD);
}

// Round 3
// 220.132 us; speedup vs baseline: 1.2506x; 1.0550x over previous
//
#include <hip/hip_runtime.h>
#include <hip/hip_bf16.h>

using bf16 = __hip_bfloat16;
typedef __bf16 bf16x8_t __attribute__((ext_vector_type(8)));
typedef float f32x4_t __attribute__((ext_vector_type(4)));

// ---------------------------------------------------------------- helpers
__device__ __forceinline__ void gl16(bf16* l, const bf16* g) {
  // async global->LDS, 16B per lane; LDS dest must be linear (base + lane*16)
  __builtin_amdgcn_global_load_lds(
      (const __attribute__((address_space(1))) unsigned int*)g,
      (__attribute__((address_space(3))) unsigned int*)l, 16, 0, 0);
}

#define BARRIER() do { asm volatile("" ::: "memory"); __builtin_amdgcn_s_barrier(); asm volatile("" ::: "memory"); } while (0)
#define WAITVM(N) asm volatile("s_waitcnt vmcnt(" #N ")" ::: "memory")

// ---------------------------------------------------------------- f32 -> bf16 convert (vectorized)
__global__ __launch_bounds__(256) void cvt_f32_bf16(const float* __restrict__ in,
                                                    bf16* __restrict__ out, int n4) {
  int i = blockIdx.x * 256 + threadIdx.x;
  if (i >= n4) return;
  float4 v = ((const float4*)in)[i];
  union { ushort4 u; bf16 b[4]; } o;
  o.b[0] = __float2bfloat16(v.x);
  o.b[1] = __float2bfloat16(v.y);
  o.b[2] = __float2bfloat16(v.z);
  o.b[3] = __float2bfloat16(v.w);
  ((ushort4*)out)[i] = o.u;
}

// ---------------------------------------------------------------- transpose + convert: in[R][C] f32 -> out[C][R] bf16
__global__ __launch_bounds__(256) void transpose_cvt(const float* __restrict__ in,
                                                     bf16* __restrict__ out, int R, int C) {
  __shared__ float t[32][33];
  int bx = blockIdx.x * 32, by = blockIdx.y * 32;
  int tx = threadIdx.x & 31, ty = threadIdx.x >> 5;  // ty 0..7
#pragma unroll
  for (int r = 0; r < 32; r += 8)
    t[ty + r][tx] = in[(size_t)(by + ty + r) * C + bx + tx];
  __syncthreads();
#pragma unroll
  for (int r = 0; r < 32; r += 8)
    out[(size_t)(bx + ty + r) * R + by + tx] = __float2bfloat16(t[tx][ty + r]);
}

// ---------------------------------------------------------------- 256x256 8-phase bf16 GEMM (T1+T2+T3+T4+T5)
// C[M,N] = A[M,K] @ Bt[N,K]^T + bias[N].  Requires M%256==0, N%256==0, K%64==0, K/64>=3.
// LDS: 2 bufs x {Ah0,Ah1,Bh0,Bh1} halves, each half [128 rows][64 cols] bf16 (16KB).
//   A-half h rows (tile-local): {region r=0,1: r*128 + h*64 + l, l=0..63}  -> row-in-half r*64+l
//   B-half h rows: {wave-region w=0..3: w*64 + h*32 + l, l=0..31}          -> row-in-half w*32+l
// Swizzle: byte-in-row ^= (row&7)<<4 (elems: col ^= (row&7)<<3). Applied on ds_read addr and
// inverse-applied on the global source for global_load_lds (linear LDS dest).

template <int MH, int NH>
__device__ __forceinline__ void phase_loads(const bf16* lb, int wr, int wc, int lr, int lg, int exr,
                                            bf16x8_t (&af)[4][2], bf16x8_t (&bfr)[2][2]) {
  const bf16* ab = lb + MH * 8192;
  const bf16* bb = lb + (2 + NH) * 8192;
#pragma unroll
  for (int mi = 0; mi < 4; ++mi) {
    int R = wr * 64 + mi * 16 + lr;
    af[mi][0] = *(const bf16x8_t*)(ab + R * 64 + ((lg * 8) ^ exr));
    af[mi][1] = *(const bf16x8_t*)(ab + R * 64 + ((32 + lg * 8) ^ exr));
  }
#pragma unroll
  for (int ni = 0; ni < 2; ++ni) {
    int R = wc * 32 + ni * 16 + lr;
    bfr[ni][0] = *(const bf16x8_t*)(bb + R * 64 + ((lg * 8) ^ exr));
    bfr[ni][1] = *(const bf16x8_t*)(bb + R * 64 + ((32 + lg * 8) ^ exr));
  }
}

template <int MH, int NH>
__device__ __forceinline__ void phase_mfma(bf16x8_t (&af)[4][2], bf16x8_t (&bfr)[2][2],
                                           f32x4_t (&acc)[8][4]) {
  __builtin_amdgcn_s_setprio(1);
#pragma unroll
  for (int mi = 0; mi < 4; ++mi)
#pragma unroll
    for (int ni = 0; ni < 2; ++ni) {
      f32x4_t& a = acc[MH * 4 + mi][NH * 2 + ni];
      a = __builtin_amdgcn_mfma_f32_16x16x32_bf16(af[mi][0], bfr[ni][0], a, 0, 0, 0);
      a = __builtin_amdgcn_mfma_f32_16x16x32_bf16(af[mi][1], bfr[ni][1], a, 0, 0, 0);
    }
  __builtin_amdgcn_s_setprio(0);
}

#define DO_PHASE(BUF, MH, NH, STAGE, WAIT) do {                          \
    bf16x8_t af[4][2], bfr[2][2];                                        \
    phase_loads<MH, NH>(lds + (BUF) * 32768, wr, wc, lr, lg, exr, af, bfr); \
    STAGE; WAIT;                                                         \
    BARRIER();                                                           \
    phase_mfma<MH, NH>(af, bfr, acc);                                    \
    BARRIER();                                                           \
  } while (0)

template <int OUT_BF16>
__global__ __launch_bounds__(512, 2) void gemm256(const bf16* __restrict__ A,
                                                  const bf16* __restrict__ Bt,
                                                  const float* __restrict__ bias,
                                                  void* __restrict__ Cv,
                                                  int M, int N, int K) {
  __shared__ __align__(16) bf16 lds[65536];  // 128 KiB
  const int tid = threadIdx.x;
  // T1: bijective XCD swizzle (grid counts are multiples of 8)
  const int nwgx = gridDim.x;
  int orig = blockIdx.y * nwgx + blockIdx.x;
  int cpx = (nwgx * gridDim.y) >> 3;
  int swzid = (orig & 7) * cpx + (orig >> 3);
  const int m0 = (swzid / nwgx) * 256, n0 = (swzid % nwgx) * 256;

  const int wid = tid >> 6, lane = tid & 63;
  const int wr = wid >> 2, wc = wid & 3;        // wave tile: rows wr*128, cols wc*64
  const int lr = lane & 15, lg = lane >> 4;
  const int exr = (lr & 7) << 3;                // read-side swizzle (elems)

  // staging constants: thread covers rows srow (+64 for chunk 1), pre-swizzled col
  const int srow = tid >> 3;                                            // 0..63
  const int colg = ((((tid & 7) * 16) ^ ((srow & 7) << 4)) >> 1);        // 0..63
  const int browc0 = (srow >> 5) * 64 + (srow & 31);

  auto stageA = [&](int b2, int h, int kt) {
    const bf16* g0 = A + (size_t)(m0 + h * 64 + srow) * K + kt * 64 + colg;
    const bf16* g1 = A + (size_t)(m0 + 128 + h * 64 + srow) * K + kt * 64 + colg;
    bf16* l = lds + b2 * 32768 + h * 8192 + tid * 8;
    gl16(l, g0); gl16(l + 4096, g1);
  };
  auto stageB = [&](int b2, int h, int kt) {
    const bf16* g0 = Bt + (size_t)(n0 + browc0 + h * 32) * K + kt * 64 + colg;
    const bf16* g1 = Bt + (size_t)(n0 + 128 + browc0 + h * 32) * K + kt * 64 + colg;
    bf16* l = lds + b2 * 32768 + (2 + h) * 8192 + tid * 8;
    gl16(l, g0); gl16(l + 4096, g1);
  };

  f32x4_t acc[8][4] = {};
  const int nt = K >> 6;  // # K-tiles (=16 here; schedule requires >=3)

  // prologue: tile0 complete + first two halves of tile1 in flight
  stageA(0, 0, 0); stageB(0, 0, 0); stageA(0, 1, 0); stageB(0, 1, 0);
  stageA(1, 0, 1); stageB(1, 0, 1);
  WAITVM(4);
  BARRIER();

  // steady state entering tile t: in-flight = {Ah0(t+1), Bh0(t+1)} (4 loads)
  for (int t = 0; t <= nt - 3; ++t) {
    const int buf = t & 1, bufn = buf ^ 1;
    DO_PHASE(buf, 0, 0, stageA(bufn, 1, t + 1), (void)0);
    DO_PHASE(buf, 0, 1, stageB(bufn, 1, t + 1), (void)0);
    DO_PHASE(buf, 1, 0, stageA(buf, 0, t + 2), (void)0);
    DO_PHASE(buf, 1, 1, stageB(buf, 0, t + 2), WAITVM(4));  // drains tile t+1 fully
  }
  {  // t = nt-2: no t+2 staging; drain everything for the last tile
    const int t = nt - 2;
    const int buf = t & 1, bufn = buf ^ 1;
    DO_PHASE(buf, 0, 0, stageA(bufn, 1, t + 1), (void)0);
    DO_PHASE(buf, 0, 1, stageB(bufn, 1, t + 1), (void)0);
    DO_PHASE(buf, 1, 0, (void)0, (void)0);
    DO_PHASE(buf, 1, 1, (void)0, WAITVM(0));
  }
  {  // t = nt-1: compute-only
    const int buf = (nt - 1) & 1;
    DO_PHASE(buf, 0, 0, (void)0, (void)0);
    DO_PHASE(buf, 0, 1, (void)0, (void)0);
    DO_PHASE(buf, 1, 0, (void)0, (void)0);
    DO_PHASE(buf, 1, 1, (void)0, (void)0);
  }

  // epilogue: D layout col=lane&15, row=(lane>>4)*4+j  [m89-verified]
#pragma unroll
  for (int n = 0; n < 4; ++n) {
    int col = n0 + wc * 64 + n * 16 + lr;
    float bv = bias[col];
#pragma unroll
    for (int m = 0; m < 8; ++m) {
      int row = m0 + wr * 128 + m * 16 + lg * 4;
#pragma unroll
      for (int j = 0; j < 4; ++j) {
        float v = acc[m][n][j] + bv;
        if (OUT_BF16)
          ((bf16*)Cv)[(size_t)(row + j) * N + col] = __float2bfloat16(v);
        else
          ((float*)Cv)[(size_t)(row + j) * N + col] = v;
      }
    }
  }
}

// ---------------------------------------------------------------- per-token head-mixing attention (MFMA)
// qkv[t][0:1024]=q, [1024:2048]=k, [2048:3072]=v ; head layout idx = h*64+d
// logits[qh][kh] = 0.125 * dot(q[qh], k[kh]); softmax over kh; out[qh][d] = sum_kh p*v[kh][d]
#define PSTR 48
__global__ __launch_bounds__(256) void attn_tok(const bf16* __restrict__ qkv,
                                                bf16* __restrict__ out) {
  __shared__ __align__(16) bf16 vs[4][1024];
  __shared__ __align__(16) bf16 ps[4][16 * PSTR];
  const int w = threadIdx.x >> 6, l = threadIdx.x & 63;
  const int t = blockIdx.x * 4 + w;
  const int lr = l & 15, lg = l >> 4;
  const bf16* base = qkv + (size_t)t * 3072;

  bf16x8_t v0 = *(const bf16x8_t*)(base + 2048 + l * 16);
  bf16x8_t v1 = *(const bf16x8_t*)(base + 2048 + l * 16 + 8);
  *(bf16x8_t*)(&vs[w][l * 16]) = v0;
  *(bf16x8_t*)(&vs[w][l * 16 + 8]) = v1;

  *(unsigned long long*)(&ps[w][(l >> 2) * PSTR + 16 + (l & 3) * 4]) = 0ULL;

  const bf16* qp = base + lr * 64 + lg * 8;
  const bf16* kp = base + 1024 + lr * 64 + lg * 8;
  bf16x8_t qa0 = *(const bf16x8_t*)qp;
  bf16x8_t ka0 = *(const bf16x8_t*)kp;
  bf16x8_t qa1 = *(const bf16x8_t*)(qp + 32);
  bf16x8_t ka1 = *(const bf16x8_t*)(kp + 32);
  f32x4_t s = {};
  s = __builtin_amdgcn_mfma_f32_16x16x32_bf16(qa0, ka0, s, 0, 0, 0);
  s = __builtin_amdgcn_mfma_f32_16x16x32_bf16(qa1, ka1, s, 0, 0, 0);

#pragma unroll
  for (int j = 0; j < 4; ++j) {
    float x = s[j] * 0.125f;
    float mx = x;
#pragma unroll
    for (int off = 8; off; off >>= 1) mx = fmaxf(mx, __shfl_xor(mx, off, 16));
    float e = __expf(x - mx);
    float sum = e;
#pragma unroll
    for (int off = 8; off; off >>= 1) sum += __shfl_xor(sum, off, 16);
    ps[w][(lg * 4 + j) * PSTR + lr] = __float2bfloat16(e / sum);
  }

  bf16x8_t pf = *(const bf16x8_t*)(&ps[w][lr * PSTR + lg * 8]);
  bf16x8_t vf[4] = {};
  if (l < 32) {
#pragma unroll
    for (int c = 0; c < 4; ++c)
#pragma unroll
      for (int j = 0; j < 8; ++j)
        vf[c][j] = (__bf16)vs[w][(lg * 8 + j) * 64 + c * 16 + lr];
  }
  f32x4_t o[4] = {};
#pragma unroll
  for (int c = 0; c < 4; ++c)
    o[c] = __builtin_amdgcn_mfma_f32_16x16x32_bf16(pf, vf[c], o[c], 0, 0, 0);

  bf16* ob = out + (size_t)t * 1024;
#pragma unroll
  for (int c = 0; c < 4; ++c)
#pragma unroll
    for (int j = 0; j < 4; ++j)
      ob[(lg * 4 + j) * 64 + c * 16 + lr] = __float2bfloat16(o[c][j]);
}

// ---------------------------------------------------------------- launch
extern "C" void kernel_launch(void* const* d_in, const int* in_sizes, int n_in,
                              void* d_out, int out_size, void* d_ws, size_t ws_size,
                              hipStream_t stream) {
  const float* x    = (const float*)d_in[0];  // [16384,1024]
  const float* Wqkv = (const float*)d_in[1];  // [1024,3072]
  const float* bqkv = (const float*)d_in[2];  // [3072]
  const float* Wout = (const float*)d_in[3];  // [1024,1024]
  const float* bout = (const float*)d_in[4];  // [1024]
  float* y = (float*)d_out;                   // [16384,1024]

  const int T = 16384, HD = 1024, N1 = 3072;

  char* ws = (char*)d_ws;
  size_t off = 0;
  bf16* xb  = (bf16*)(ws + off); off += (size_t)T * HD * 2;
  bf16* w1t = (bf16*)(ws + off); off += (size_t)N1 * HD * 2;
  bf16* w2t = (bf16*)(ws + off); off += (size_t)HD * HD * 2;
  bf16* qkv = (bf16*)(ws + off); off += (size_t)T * N1 * 2;
  if (ws_size < off) return;
  bf16* ao = xb;  // xb dead after GEMM1; reuse as attention output

  cvt_f32_bf16<<<(T * HD / 4 + 255) / 256, 256, 0, stream>>>(x, xb, T * HD / 4);
  transpose_cvt<<<dim3(N1 / 32, HD / 32), 256, 0, stream>>>(Wqkv, w1t, HD, N1);
  transpose_cvt<<<dim3(HD / 32, HD / 32), 256, 0, stream>>>(Wout, w2t, HD, HD);

  gemm256<1><<<dim3(N1 / 256, T / 256), 512, 0, stream>>>(xb, w1t, bqkv, qkv, T, N1, HD);
  attn_tok<<<T / 4, 256, 0, stream>>>(qkv, ao);
  gemm256<0><<<dim3(HD / 256, T / 256), 512, 0, stream>>>(ao, w2t, bout, y, T, HD, HD);
}

// Round 4
// 219.536 us; speedup vs baseline: 1.2540x; 1.0027x over previous
//
#include <hip/hip_runtime.h>
#include <hip/hip_bf16.h>

using bf16 = __hip_bfloat16;
typedef __bf16 bf16x8_t __attribute__((ext_vector_type(8)));
typedef float f32x4_t __attribute__((ext_vector_type(4)));

// ---------------------------------------------------------------- helpers
__device__ __forceinline__ void gl16(bf16* l, const bf16* g) {
  // async global->LDS, 16B per lane; LDS dest must be linear (base + lane*16)
  __builtin_amdgcn_global_load_lds(
      (const __attribute__((address_space(1))) unsigned int*)g,
      (__attribute__((address_space(3))) unsigned int*)l, 16, 0, 0);
}

#define BARRIER() do { asm volatile("" ::: "memory"); __builtin_amdgcn_s_barrier(); asm volatile("" ::: "memory"); } while (0)
#define WAITVM(N) asm volatile("s_waitcnt vmcnt(" #N ")" ::: "memory")

// ---------------------------------------------------------------- f32 -> bf16 convert (vectorized)
__global__ __launch_bounds__(256) void cvt_f32_bf16(const float* __restrict__ in,
                                                    bf16* __restrict__ out, int n4) {
  int i = blockIdx.x * 256 + threadIdx.x;
  if (i >= n4) return;
  float4 v = ((const float4*)in)[i];
  union { ushort4 u; bf16 b[4]; } o;
  o.b[0] = __float2bfloat16(v.x);
  o.b[1] = __float2bfloat16(v.y);
  o.b[2] = __float2bfloat16(v.z);
  o.b[3] = __float2bfloat16(v.w);
  ((ushort4*)out)[i] = o.u;
}

// ---------------------------------------------------------------- transpose + convert: in[R][C] f32 -> out[C][R] bf16
__global__ __launch_bounds__(256) void transpose_cvt(const float* __restrict__ in,
                                                     bf16* __restrict__ out, int R, int C) {
  __shared__ float t[32][33];
  int bx = blockIdx.x * 32, by = blockIdx.y * 32;
  int tx = threadIdx.x & 31, ty = threadIdx.x >> 5;  // ty 0..7
#pragma unroll
  for (int r = 0; r < 32; r += 8)
    t[ty + r][tx] = in[(size_t)(by + ty + r) * C + bx + tx];
  __syncthreads();
#pragma unroll
  for (int r = 0; r < 32; r += 8)
    out[(size_t)(bx + ty + r) * R + by + tx] = __float2bfloat16(t[tx][ty + r]);
}

// ---------------------------------------------------------------- 256x256 8-phase bf16 GEMM, persistent blocks
// C[M=16384, N=NWGX*256] = A @ Bt^T + bias. K fixed at 1024 (nt=16).
// Grid = 256 blocks x 512 thr; each block computes TT = NWGX/4 output tiles as one
// flattened G = TT*16-step pipeline (never drains across tile boundaries).
// LDS: 2 bufs x {Ah0,Ah1,Bh0,Bh1} halves, each [128 rows][64 cols] bf16.
// Swizzle (T2): 8-elem chunk index ^= (row&7), both staging-source and ds_read sides.

template <int MH, int NH>
__device__ __forceinline__ void phase_loads(const bf16* lb, int wr, int wc, int lr, int lg, int exr,
                                            bf16x8_t (&af)[4][2], bf16x8_t (&bfr)[2][2]) {
  const bf16* ab = lb + MH * 8192;
  const bf16* bb = lb + (2 + NH) * 8192;
#pragma unroll
  for (int mi = 0; mi < 4; ++mi) {
    int R = wr * 64 + mi * 16 + lr;
    af[mi][0] = *(const bf16x8_t*)(ab + R * 64 + ((lg * 8) ^ exr));
    af[mi][1] = *(const bf16x8_t*)(ab + R * 64 + ((32 + lg * 8) ^ exr));
  }
#pragma unroll
  for (int ni = 0; ni < 2; ++ni) {
    int R = wc * 32 + ni * 16 + lr;
    bfr[ni][0] = *(const bf16x8_t*)(bb + R * 64 + ((lg * 8) ^ exr));
    bfr[ni][1] = *(const bf16x8_t*)(bb + R * 64 + ((32 + lg * 8) ^ exr));
  }
}

template <int MH, int NH>
__device__ __forceinline__ void phase_mfma(bf16x8_t (&af)[4][2], bf16x8_t (&bfr)[2][2],
                                           f32x4_t (&acc)[8][4]) {
  __builtin_amdgcn_s_setprio(1);
#pragma unroll
  for (int mi = 0; mi < 4; ++mi)
#pragma unroll
    for (int ni = 0; ni < 2; ++ni) {
      f32x4_t& a = acc[MH * 4 + mi][NH * 2 + ni];
      a = __builtin_amdgcn_mfma_f32_16x16x32_bf16(af[mi][0], bfr[ni][0], a, 0, 0, 0);
      a = __builtin_amdgcn_mfma_f32_16x16x32_bf16(af[mi][1], bfr[ni][1], a, 0, 0, 0);
    }
  __builtin_amdgcn_s_setprio(0);
}

#define DO_PHASE(BUF, MH, NH, STAGE, WAIT) do {                          \
    bf16x8_t af[4][2], bfr[2][2];                                        \
    phase_loads<MH, NH>(lds + (BUF) * 32768, wr, wc, lr, lg, exr, af, bfr); \
    STAGE; WAIT;                                                         \
    BARRIER();                                                           \
    phase_mfma<MH, NH>(af, bfr, acc);                                    \
    BARRIER();                                                           \
  } while (0)

template <int OUT_BF16, int NWGX>
__global__ __launch_bounds__(512, 2) void gemm256p(const bf16* __restrict__ A,
                                                   const bf16* __restrict__ Bt,
                                                   const float* __restrict__ bias,
                                                   void* __restrict__ Cv) {
  constexpr int K = 1024;
  constexpr int N = NWGX * 256;
  constexpr int TT = NWGX / 4;     // output tiles per block (grid is always 256)
  constexpr int G = TT * 16;       // flattened K-steps
  constexpr int CPX = NWGX * 8;    // tiles per XCD chunk = 64*NWGX/8

  __shared__ __align__(16) bf16 lds[65536];  // 128 KiB
  const int tid = threadIdx.x;
  const int bx = blockIdx.x;

  const int wid = tid >> 6, lane = tid & 63;
  const int wr = wid >> 2, wc = wid & 3;        // wave tile: rows wr*128, cols wc*64
  const int lr = lane & 15, lg = lane >> 4;
  const int exr = (lr & 7) << 3;                // read-side swizzle (elems)

  const int srow = tid >> 3;                                        // 0..63
  const int colg = ((((tid & 7) * 16) ^ ((srow & 7) << 4)) >> 1);    // pre-swizzled col (elems)
  const int browc0 = (srow >> 5) * 64 + (srow & 31);

  // tile-id -> (m0, n0) with bijective XCD swizzle (HW: XCD = orig_block % 8)
  auto tileMN = [&](int tt, int& m0, int& n0) {
    int orig = bx + (tt << 8);
    int swz = (orig & 7) * CPX + (orig >> 3);
    m0 = (swz / NWGX) * 256;
    n0 = (swz % NWGX) * 256;
  };

  auto stageA = [&](int g, int h) {  // stage A-half h of K-step g (no-op past end)
    if (g >= G) return;
    int m0, n0; tileMN(g >> 4, m0, n0);
    const bf16* g0 = A + (size_t)(m0 + h * 64 + srow) * K + (g & 15) * 64 + colg;
    bf16* l = lds + (g & 1) * 32768 + h * 8192 + tid * 8;
    gl16(l, g0); gl16(l + 4096, g0 + (size_t)128 * K);
  };
  auto stageB = [&](int g, int h) {
    if (g >= G) return;
    int m0, n0; tileMN(g >> 4, m0, n0);
    const bf16* g0 = Bt + (size_t)(n0 + browc0 + h * 32) * K + (g & 15) * 64 + colg;
    bf16* l = lds + (g & 1) * 32768 + (2 + h) * 8192 + tid * 8;
    gl16(l, g0); gl16(l + 4096, g0 + (size_t)128 * K);
  };

  f32x4_t acc[8][4] = {};

  // prologue: K-step 0 complete + h0 of step 1 in flight
  stageA(0, 0); stageB(0, 0); stageA(0, 1); stageB(0, 1);
  stageA(1, 0); stageB(1, 0);
  WAITVM(4);
  BARRIER();

  for (int g = 0; g < G; ++g) {
    const int buf = g & 1;
    DO_PHASE(buf, 0, 0, stageA(g + 1, 1), (void)0);
    DO_PHASE(buf, 0, 1, stageB(g + 1, 1), (void)0);
    DO_PHASE(buf, 1, 0, stageA(g + 2, 0), (void)0);
    if (g < G - 2) {
      DO_PHASE(buf, 1, 1, stageB(g + 2, 0), WAITVM(4));  // drains step g+1 fully
    } else if (g == G - 2) {
      DO_PHASE(buf, 1, 1, (void)0, WAITVM(0));
    } else {
      DO_PHASE(buf, 1, 1, (void)0, (void)0);
    }

    if ((g & 15) == 15) {
      // dump accumulator for finished output tile, n innermost (line-complete stores)
      int m0, n0; tileMN(g >> 4, m0, n0);
#pragma unroll
      for (int m = 0; m < 8; ++m) {
        int row = m0 + wr * 128 + m * 16 + lg * 4;
#pragma unroll
        for (int j = 0; j < 4; ++j) {
#pragma unroll
          for (int n = 0; n < 4; ++n) {
            int col = n0 + wc * 64 + n * 16 + lr;
            float v = acc[m][n][j] + bias[col];
            if (OUT_BF16)
              ((bf16*)Cv)[(size_t)(row + j) * N + col] = __float2bfloat16(v);
            else
              ((float*)Cv)[(size_t)(row + j) * N + col] = v;
            acc[m][n][j] = 0.f;
          }
        }
      }
    }
  }
}

// ---------------------------------------------------------------- per-token head-mixing attention (MFMA)
// qkv[t][0:1024]=q, [1024:2048]=k, [2048:3072]=v ; head layout idx = h*64+d
// logits[qh][kh] = 0.125 * dot(q[qh], k[kh]); softmax over kh; out[qh][d] = sum_kh p*v[kh][d]
#define PSTR 48
__global__ __launch_bounds__(256) void attn_tok(const bf16* __restrict__ qkv,
                                                bf16* __restrict__ out) {
  __shared__ __align__(16) bf16 vs[4][1024];
  __shared__ __align__(16) bf16 ps[4][16 * PSTR];
  const int w = threadIdx.x >> 6, l = threadIdx.x & 63;
  const int t = blockIdx.x * 4 + w;
  const int lr = l & 15, lg = l >> 4;
  const bf16* base = qkv + (size_t)t * 3072;

  bf16x8_t v0 = *(const bf16x8_t*)(base + 2048 + l * 16);
  bf16x8_t v1 = *(const bf16x8_t*)(base + 2048 + l * 16 + 8);
  *(bf16x8_t*)(&vs[w][l * 16]) = v0;
  *(bf16x8_t*)(&vs[w][l * 16 + 8]) = v1;

  *(unsigned long long*)(&ps[w][(l >> 2) * PSTR + 16 + (l & 3) * 4]) = 0ULL;

  const bf16* qp = base + lr * 64 + lg * 8;
  const bf16* kp = base + 1024 + lr * 64 + lg * 8;
  bf16x8_t qa0 = *(const bf16x8_t*)qp;
  bf16x8_t ka0 = *(const bf16x8_t*)kp;
  bf16x8_t qa1 = *(const bf16x8_t*)(qp + 32);
  bf16x8_t ka1 = *(const bf16x8_t*)(kp + 32);
  f32x4_t s = {};
  s = __builtin_amdgcn_mfma_f32_16x16x32_bf16(qa0, ka0, s, 0, 0, 0);
  s = __builtin_amdgcn_mfma_f32_16x16x32_bf16(qa1, ka1, s, 0, 0, 0);

#pragma unroll
  for (int j = 0; j < 4; ++j) {
    float x = s[j] * 0.125f;
    float mx = x;
#pragma unroll
    for (int off = 8; off; off >>= 1) mx = fmaxf(mx, __shfl_xor(mx, off, 16));
    float e = __expf(x - mx);
    float sum = e;
#pragma unroll
    for (int off = 8; off; off >>= 1) sum += __shfl_xor(sum, off, 16);
    ps[w][(lg * 4 + j) * PSTR + lr] = __float2bfloat16(e / sum);
  }

  bf16x8_t pf = *(const bf16x8_t*)(&ps[w][lr * PSTR + lg * 8]);
  bf16x8_t vf[4] = {};
  if (l < 32) {
#pragma unroll
    for (int c = 0; c < 4; ++c)
#pragma unroll
      for (int j = 0; j < 8; ++j)
        vf[c][j] = (__bf16)vs[w][(lg * 8 + j) * 64 + c * 16 + lr];
  }
  f32x4_t o[4] = {};
#pragma unroll
  for (int c = 0; c < 4; ++c)
    o[c] = __builtin_amdgcn_mfma_f32_16x16x32_bf16(pf, vf[c], o[c], 0, 0, 0);

  bf16* ob = out + (size_t)t * 1024;
#pragma unroll
  for (int c = 0; c < 4; ++c)
#pragma unroll
    for (int j = 0; j < 4; ++j)
      ob[(lg * 4 + j) * 64 + c * 16 + lr] = __float2bfloat16(o[c][j]);
}

// ---------------------------------------------------------------- launch
extern "C" void kernel_launch(void* const* d_in, const int* in_sizes, int n_in,
                              void* d_out, int out_size, void* d_ws, size_t ws_size,
                              hipStream_t stream) {
  const float* x    = (const float*)d_in[0];  // [16384,1024]
  const float* Wqkv = (const float*)d_in[1];  // [1024,3072]
  const float* bqkv = (const float*)d_in[2];  // [3072]
  const float* Wout = (const float*)d_in[3];  // [1024,1024]
  const float* bout = (const float*)d_in[4];  // [1024]
  float* y = (float*)d_out;                   // [16384,1024]

  const int T = 16384, HD = 1024, N1 = 3072;

  char* ws = (char*)d_ws;
  size_t off = 0;
  bf16* xb  = (bf16*)(ws + off); off += (size_t)T * HD * 2;
  bf16* w1t = (bf16*)(ws + off); off += (size_t)N1 * HD * 2;
  bf16* w2t = (bf16*)(ws + off); off += (size_t)HD * HD * 2;
  bf16* qkv = (bf16*)(ws + off); off += (size_t)T * N1 * 2;
  if (ws_size < off) return;
  bf16* ao = xb;  // xb dead after GEMM1; reuse as attention output

  cvt_f32_bf16<<<(T * HD / 4 + 255) / 256, 256, 0, stream>>>(x, xb, T * HD / 4);
  transpose_cvt<<<dim3(N1 / 32, HD / 32), 256, 0, stream>>>(Wqkv, w1t, HD, N1);
  transpose_cvt<<<dim3(HD / 32, HD / 32), 256, 0, stream>>>(Wout, w2t, HD, HD);

  gemm256p<1, 12><<<256, 512, 0, stream>>>(xb, w1t, bqkv, qkv);
  attn_tok<<<T / 4, 256, 0, stream>>>(qkv, ao);
  gemm256p<0, 4><<<256, 512, 0, stream>>>(ao, w2t, bout, y);
}

// Round 5
// 207.594 us; speedup vs baseline: 1.3261x; 1.0575x over previous
//
#include <hip/hip_runtime.h>
#include <hip/hip_bf16.h>

using bf16 = __hip_bfloat16;
typedef __bf16 bf16x8_t __attribute__((ext_vector_type(8)));
typedef float f32x4_t __attribute__((ext_vector_type(4)));

// ---------------------------------------------------------------- helpers
__device__ __forceinline__ void gl16(bf16* l, const bf16* g) {
  // async global->LDS, 16B per lane; LDS dest must be linear (base + lane*16)
  __builtin_amdgcn_global_load_lds(
      (const __attribute__((address_space(1))) unsigned int*)g,
      (__attribute__((address_space(3))) unsigned int*)l, 16, 0, 0);
}

#define BARRIER() do { asm volatile("" ::: "memory"); __builtin_amdgcn_s_barrier(); asm volatile("" ::: "memory"); } while (0)
#define WAITVM(N) asm volatile("s_waitcnt vmcnt(" #N ")" ::: "memory")
#define SCHED0() __builtin_amdgcn_sched_barrier(0)

// ---------------------------------------------------------------- f32 -> bf16 convert (vectorized)
__global__ __launch_bounds__(256) void cvt_f32_bf16(const float* __restrict__ in,
                                                    bf16* __restrict__ out, int n4) {
  int i = blockIdx.x * 256 + threadIdx.x;
  if (i >= n4) return;
  float4 v = ((const float4*)in)[i];
  union { ushort4 u; bf16 b[4]; } o;
  o.b[0] = __float2bfloat16(v.x);
  o.b[1] = __float2bfloat16(v.y);
  o.b[2] = __float2bfloat16(v.z);
  o.b[3] = __float2bfloat16(v.w);
  ((ushort4*)out)[i] = o.u;
}

// ---------------------------------------------------------------- transpose + convert: in[R][C] f32 -> out[C][R] bf16
__global__ __launch_bounds__(256) void transpose_cvt(const float* __restrict__ in,
                                                     bf16* __restrict__ out, int R, int C) {
  __shared__ float t[32][33];
  int bx = blockIdx.x * 32, by = blockIdx.y * 32;
  int tx = threadIdx.x & 31, ty = threadIdx.x >> 5;  // ty 0..7
#pragma unroll
  for (int r = 0; r < 32; r += 8)
    t[ty + r][tx] = in[(size_t)(by + ty + r) * C + bx + tx];
  __syncthreads();
#pragma unroll
  for (int r = 0; r < 32; r += 8)
    out[(size_t)(bx + ty + r) * R + by + tx] = __float2bfloat16(t[tx][ty + r]);
}

// ---------------------------------------------------------------- 256x256 8-phase bf16 GEMM, persistent + reg-pipelined
// C[M=16384, N=NWGX*256] = A @ Bt^T + bias. K fixed 1024 (16 K-steps/tile), grid 256x512thr.
// Each K-step of 64: 4 phases (C-quadrants). Fragment sets af1(Ah0) af2(Ah1) b0(Bh0) b1(Bh1)
// are each LDS-read ONCE per K-step, issued inside the PREVIOUS phase's MFMA window so the
// ds_read latency hides under MFMA. Cross-step reads issue after the WAITVM(4)+barrier.

__device__ __forceinline__ void readA(const bf16* lb, int half, int wr, int lr, int lg, int exr,
                                      bf16x8_t (&af)[4][2]) {
  const bf16* ab = lb + half * 8192;
#pragma unroll
  for (int mi = 0; mi < 4; ++mi) {
    int R = wr * 64 + mi * 16 + lr;
    af[mi][0] = *(const bf16x8_t*)(ab + R * 64 + ((lg * 8) ^ exr));
    af[mi][1] = *(const bf16x8_t*)(ab + R * 64 + ((32 + lg * 8) ^ exr));
  }
}
__device__ __forceinline__ void readB(const bf16* lb, int half, int wc, int lr, int lg, int exr,
                                      bf16x8_t (&bfr)[2][2]) {
  const bf16* bb = lb + (2 + half) * 8192;
#pragma unroll
  for (int ni = 0; ni < 2; ++ni) {
    int R = wc * 32 + ni * 16 + lr;
    bfr[ni][0] = *(const bf16x8_t*)(bb + R * 64 + ((lg * 8) ^ exr));
    bfr[ni][1] = *(const bf16x8_t*)(bb + R * 64 + ((32 + lg * 8) ^ exr));
  }
}

template <int MH, int NH>
__device__ __forceinline__ void mfma16(bf16x8_t (&af)[4][2], bf16x8_t (&bfr)[2][2],
                                       f32x4_t (&acc)[8][4]) {
  __builtin_amdgcn_s_setprio(1);
#pragma unroll
  for (int mi = 0; mi < 4; ++mi)
#pragma unroll
    for (int ni = 0; ni < 2; ++ni) {
      f32x4_t& a = acc[MH * 4 + mi][NH * 2 + ni];
      a = __builtin_amdgcn_mfma_f32_16x16x32_bf16(af[mi][0], bfr[ni][0], a, 0, 0, 0);
      a = __builtin_amdgcn_mfma_f32_16x16x32_bf16(af[mi][1], bfr[ni][1], a, 0, 0, 0);
    }
  __builtin_amdgcn_s_setprio(0);
}

template <int OUT_BF16, int NWGX>
__global__ __launch_bounds__(512, 2) void gemm256p(const bf16* __restrict__ A,
                                                   const bf16* __restrict__ Bt,
                                                   const float* __restrict__ bias,
                                                   void* __restrict__ Cv) {
  constexpr int K = 1024;
  constexpr int N = NWGX * 256;
  constexpr int TT = NWGX / 4;     // output tiles per block (grid fixed at 256)
  constexpr int G = TT * 16;       // flattened K-steps
  constexpr int CPX = NWGX * 8;    // tiles per XCD chunk

  __shared__ __align__(16) bf16 lds[65536];  // 128 KiB
  const int tid = threadIdx.x;
  const int bx = blockIdx.x;

  const int wid = tid >> 6, lane = tid & 63;
  const int wr = wid >> 2, wc = wid & 3;
  const int lr = lane & 15, lg = lane >> 4;
  const int exr = (lr & 7) << 3;

  const int srow = tid >> 3;
  const int colg = ((((tid & 7) * 16) ^ ((srow & 7) << 4)) >> 1);
  const int browc0 = (srow >> 5) * 64 + (srow & 31);

  auto tileMN = [&](int tt, int& m0, int& n0) {
    int orig = bx + (tt << 8);
    int swz = (orig & 7) * CPX + (orig >> 3);
    m0 = (swz / NWGX) * 256;
    n0 = (swz % NWGX) * 256;
  };

  auto stageA = [&](int g, int h) {
    if (g >= G) return;
    int m0, n0; tileMN(g >> 4, m0, n0);
    const bf16* g0 = A + (size_t)(m0 + h * 64 + srow) * K + (g & 15) * 64 + colg;
    bf16* l = lds + (g & 1) * 32768 + h * 8192 + tid * 8;
    gl16(l, g0); gl16(l + 4096, g0 + (size_t)128 * K);
  };
  auto stageB = [&](int g, int h) {
    if (g >= G) return;
    int m0, n0; tileMN(g >> 4, m0, n0);
    const bf16* g0 = Bt + (size_t)(n0 + browc0 + h * 32) * K + (g & 15) * 64 + colg;
    bf16* l = lds + (g & 1) * 32768 + (2 + h) * 8192 + tid * 8;
    gl16(l, g0); gl16(l + 4096, g0 + (size_t)128 * K);
  };

  f32x4_t acc[8][4] = {};
  bf16x8_t af1[4][2], af2[4][2], b0[2][2], b1[2][2];

  // prologue: K-step 0 fully staged + {Ah0,Bh0}(1) in flight
  stageA(0, 0); stageB(0, 0); stageA(0, 1); stageB(0, 1);
  stageA(1, 0); stageB(1, 0);
  WAITVM(4);
  BARRIER();
  readA(lds, 0, wr, lr, lg, exr, af1);   // Ah0(0)
  readB(lds, 0, wc, lr, lg, exr, b0);    // Bh0(0)

  for (int g = 0; g < G; ++g) {
    const bf16* cb = lds + (g & 1) * 32768;
    const bf16* nb = lds + ((g & 1) ^ 1) * 32768;

    // phase 1: quadrant (0,0) = af1 x b0 ; prefetch b1 (Bh1 cur)
    stageA(g + 1, 1);
    BARRIER();
    readB(cb, 1, wc, lr, lg, exr, b1);
    SCHED0();
    mfma16<0, 0>(af1, b0, acc);
    BARRIER();

    // phase 2: quadrant (0,1) = af1 x b1 ; prefetch af2 (Ah1 cur)
    stageB(g + 1, 1);
    BARRIER();
    readA(cb, 1, wr, lr, lg, exr, af2);
    SCHED0();
    mfma16<0, 1>(af1, b1, acc);
    BARRIER();

    // phase 3: quadrant (1,0) = af2 x b0 ; nothing to prefetch
    stageA(g + 2, 0);
    BARRIER();
    mfma16<1, 0>(af2, b0, acc);
    BARRIER();

    // phase 4: quadrant (1,1) = af2 x b1 ; prefetch af1,b0 from NEXT buffer
    stageB(g + 2, 0);
    if (g < G - 2) { WAITVM(4); } else { WAITVM(0); }
    BARRIER();
    readA(nb, 0, wr, lr, lg, exr, af1);
    readB(nb, 0, wc, lr, lg, exr, b0);
    SCHED0();
    mfma16<1, 1>(af2, b1, acc);
    BARRIER();

    if ((g & 15) == 15) {
      // dump finished tile; n innermost so each 64B C-line completes back-to-back
      int m0, n0; tileMN(g >> 4, m0, n0);
      float bv[4];
#pragma unroll
      for (int n = 0; n < 4; ++n) bv[n] = bias[n0 + wc * 64 + n * 16 + lr];
#pragma unroll
      for (int m = 0; m < 8; ++m) {
        int row = m0 + wr * 128 + m * 16 + lg * 4;
#pragma unroll
        for (int j = 0; j < 4; ++j) {
#pragma unroll
          for (int n = 0; n < 4; ++n) {
            int col = n0 + wc * 64 + n * 16 + lr;
            float v = acc[m][n][j] + bv[n];
            if (OUT_BF16)
              ((bf16*)Cv)[(size_t)(row + j) * N + col] = __float2bfloat16(v);
            else
              ((float*)Cv)[(size_t)(row + j) * N + col] = v;
            acc[m][n][j] = 0.f;
          }
        }
      }
    }
  }
}

// ---------------------------------------------------------------- per-token head-mixing attention (MFMA)
// qkv[t][0:1024]=q, [1024:2048]=k, [2048:3072]=v ; head layout idx = h*64+d
// logits[qh][kh] = 0.125 * dot(q[qh], k[kh]); softmax over kh; out[qh][d] = sum_kh p*v[kh][d]
#define PSTR 48
__global__ __launch_bounds__(256) void attn_tok(const bf16* __restrict__ qkv,
                                                bf16* __restrict__ out) {
  __shared__ __align__(16) bf16 vs[4][1024];
  __shared__ __align__(16) bf16 ps[4][16 * PSTR];
  const int w = threadIdx.x >> 6, l = threadIdx.x & 63;
  const int t = blockIdx.x * 4 + w;
  const int lr = l & 15, lg = l >> 4;
  const bf16* base = qkv + (size_t)t * 3072;

  bf16x8_t v0 = *(const bf16x8_t*)(base + 2048 + l * 16);
  bf16x8_t v1 = *(const bf16x8_t*)(base + 2048 + l * 16 + 8);
  *(bf16x8_t*)(&vs[w][l * 16]) = v0;
  *(bf16x8_t*)(&vs[w][l * 16 + 8]) = v1;

  *(unsigned long long*)(&ps[w][(l >> 2) * PSTR + 16 + (l & 3) * 4]) = 0ULL;

  const bf16* qp = base + lr * 64 + lg * 8;
  const bf16* kp = base + 1024 + lr * 64 + lg * 8;
  bf16x8_t qa0 = *(const bf16x8_t*)qp;
  bf16x8_t ka0 = *(const bf16x8_t*)kp;
  bf16x8_t qa1 = *(const bf16x8_t*)(qp + 32);
  bf16x8_t ka1 = *(const bf16x8_t*)(kp + 32);
  f32x4_t s = {};
  s = __builtin_amdgcn_mfma_f32_16x16x32_bf16(qa0, ka0, s, 0, 0, 0);
  s = __builtin_amdgcn_mfma_f32_16x16x32_bf16(qa1, ka1, s, 0, 0, 0);

#pragma unroll
  for (int j = 0; j < 4; ++j) {
    float x = s[j] * 0.125f;
    float mx = x;
#pragma unroll
    for (int off = 8; off; off >>= 1) mx = fmaxf(mx, __shfl_xor(mx, off, 16));
    float e = __expf(x - mx);
    float sum = e;
#pragma unroll
    for (int off = 8; off; off >>= 1) sum += __shfl_xor(sum, off, 16);
    ps[w][(lg * 4 + j) * PSTR + lr] = __float2bfloat16(e / sum);
  }

  bf16x8_t pf = *(const bf16x8_t*)(&ps[w][lr * PSTR + lg * 8]);
  bf16x8_t vf[4] = {};
  if (l < 32) {
#pragma unroll
    for (int c = 0; c < 4; ++c)
#pragma unroll
      for (int j = 0; j < 8; ++j)
        vf[c][j] = (__bf16)vs[w][(lg * 8 + j) * 64 + c * 16 + lr];
  }
  f32x4_t o[4] = {};
#pragma unroll
  for (int c = 0; c < 4; ++c)
    o[c] = __builtin_amdgcn_mfma_f32_16x16x32_bf16(pf, vf[c], o[c], 0, 0, 0);

  bf16* ob = out + (size_t)t * 1024;
#pragma unroll
  for (int c = 0; c < 4; ++c)
#pragma unroll
    for (int j = 0; j < 4; ++j)
      ob[(lg * 4 + j) * 64 + c * 16 + lr] = __float2bfloat16(o[c][j]);
}

// ---------------------------------------------------------------- launch
extern "C" void kernel_launch(void* const* d_in, const int* in_sizes, int n_in,
                              void* d_out, int out_size, void* d_ws, size_t ws_size,
                              hipStream_t stream) {
  const float* x    = (const float*)d_in[0];  // [16384,1024]
  const float* Wqkv = (const float*)d_in[1];  // [1024,3072]
  const float* bqkv = (const float*)d_in[2];  // [3072]
  const float* Wout = (const float*)d_in[3];  // [1024,1024]
  const float* bout = (const float*)d_in[4];  // [1024]
  float* y = (float*)d_out;                   // [16384,1024]

  const int T = 16384, HD = 1024, N1 = 3072;

  char* ws = (char*)d_ws;
  size_t off = 0;
  bf16* xb  = (bf16*)(ws + off); off += (size_t)T * HD * 2;
  bf16* w1t = (bf16*)(ws + off); off += (size_t)N1 * HD * 2;
  bf16* w2t = (bf16*)(ws + off); off += (size_t)HD * HD * 2;
  bf16* qkv = (bf16*)(ws + off); off += (size_t)T * N1 * 2;
  if (ws_size < off) return;
  bf16* ao = xb;  // xb dead after GEMM1; reuse as attention output

  cvt_f32_bf16<<<(T * HD / 4 + 255) / 256, 256, 0, stream>>>(x, xb, T * HD / 4);
  transpose_cvt<<<dim3(N1 / 32, HD / 32), 256, 0, stream>>>(Wqkv, w1t, HD, N1);
  transpose_cvt<<<dim3(HD / 32, HD / 32), 256, 0, stream>>>(Wout, w2t, HD, HD);

  gemm256p<1, 12><<<256, 512, 0, stream>>>(xb, w1t, bqkv, qkv);
  attn_tok<<<T / 4, 256, 0, stream>>>(qkv, ao);
  gemm256p<0, 4><<<256, 512, 0, stream>>>(ao, w2t, bout, y);
}

// Round 6
// 199.178 us; speedup vs baseline: 1.3821x; 1.0423x over previous
//
#include <hip/hip_runtime.h>
#include <hip/hip_bf16.h>

using bf16 = __hip_bfloat16;
typedef __bf16 bf16x8_t __attribute__((ext_vector_type(8)));
typedef float f32x4_t __attribute__((ext_vector_type(4)));

// ---------------------------------------------------------------- helpers
__device__ __forceinline__ void gl16(bf16* l, const bf16* g) {
  // async global->LDS, 16B per lane; LDS dest must be linear (base + lane*16)
  __builtin_amdgcn_global_load_lds(
      (const __attribute__((address_space(1))) unsigned int*)g,
      (__attribute__((address_space(3))) unsigned int*)l, 16, 0, 0);
}

#define BARRIER() do { asm volatile("" ::: "memory"); __builtin_amdgcn_s_barrier(); asm volatile("" ::: "memory"); } while (0)
#define WAITVM(N) asm volatile("s_waitcnt vmcnt(" #N ")" ::: "memory")
#define SCHED0() __builtin_amdgcn_sched_barrier(0)

// ---------------------------------------------------------------- fused prep: cvt x + transpose both W
// job0: x f32 -> bf16 (16384 blocks); job1: Wqkv [1024][3072] -> w1t [3072][1024] (3072 blocks);
// job2: Wout [1024][1024] -> w2t (1024 blocks)
__global__ __launch_bounds__(256) void prep_fused(const float* __restrict__ x,
                                                  const float* __restrict__ Wqkv,
                                                  const float* __restrict__ Wout,
                                                  bf16* __restrict__ xb,
                                                  bf16* __restrict__ w1t,
                                                  bf16* __restrict__ w2t) {
  __shared__ float t[32][33];
  const int bid = blockIdx.x;
  if (bid < 16384) {  // cvt: 4 f32 per thread
    int i = bid * 256 + threadIdx.x;
    float4 v = ((const float4*)x)[i];
    union { ushort4 u; bf16 b[4]; } o;
    o.b[0] = __float2bfloat16(v.x);
    o.b[1] = __float2bfloat16(v.y);
    o.b[2] = __float2bfloat16(v.z);
    o.b[3] = __float2bfloat16(v.w);
    ((ushort4*)xb)[i] = o.u;
    return;
  }
  const float* in; bf16* out; int R, C, gx, gy;
  if (bid < 16384 + 3072) {
    int idx = bid - 16384; in = Wqkv; out = w1t; R = 1024; C = 3072;
    gx = idx % 96; gy = idx / 96;
  } else {
    int idx = bid - 16384 - 3072; in = Wout; out = w2t; R = 1024; C = 1024;
    gx = idx & 31; gy = idx >> 5;
  }
  int bx = gx * 32, by = gy * 32;
  int tx = threadIdx.x & 31, ty = threadIdx.x >> 5;  // ty 0..7
#pragma unroll
  for (int r = 0; r < 32; r += 8)
    t[ty + r][tx] = in[(size_t)(by + ty + r) * C + bx + tx];
  __syncthreads();
#pragma unroll
  for (int r = 0; r < 32; r += 8)
    out[(size_t)(bx + ty + r) * R + by + tx] = __float2bfloat16(t[tx][ty + r]);
}

// ---------------------------------------------------------------- 256x256 4-phase/1-barrier bf16 GEMM, persistent
// C[M=16384, N=NWGX*256] = A @ Bt^T + bias. K fixed 1024, grid 256x512thr.
// Per K-step of 64: 4 phases (C-quadrants), ONE barrier each. Fragment sets af1(Ah0)
// af2(Ah1) b0(Bh0) b1(Bh1) each LDS-read once per K-step, one phase ahead of use.
// Hazard audit (stage-write vs laggard reads, single-barrier): stage targets per phase
// {nb.A1, nb.B1, cb.A0, cb.B0} are disjoint from the concurrent/lagging read regions
// {cb.B1, cb.A1, -, nb.A0+nb.B0}; reuse distance of every LDS region >= 2 barriers.

__device__ __forceinline__ void readA(const bf16* lb, int half, int wr, int lr, int lg, int exr,
                                      bf16x8_t (&af)[4][2]) {
  const bf16* ab = lb + half * 8192;
#pragma unroll
  for (int mi = 0; mi < 4; ++mi) {
    int R = wr * 64 + mi * 16 + lr;
    af[mi][0] = *(const bf16x8_t*)(ab + R * 64 + ((lg * 8) ^ exr));
    af[mi][1] = *(const bf16x8_t*)(ab + R * 64 + ((32 + lg * 8) ^ exr));
  }
}
__device__ __forceinline__ void readB(const bf16* lb, int half, int wc, int lr, int lg, int exr,
                                      bf16x8_t (&bfr)[2][2]) {
  const bf16* bb = lb + (2 + half) * 8192;
#pragma unroll
  for (int ni = 0; ni < 2; ++ni) {
    int R = wc * 32 + ni * 16 + lr;
    bfr[ni][0] = *(const bf16x8_t*)(bb + R * 64 + ((lg * 8) ^ exr));
    bfr[ni][1] = *(const bf16x8_t*)(bb + R * 64 + ((32 + lg * 8) ^ exr));
  }
}

template <int MH, int NH>
__device__ __forceinline__ void mfma16(bf16x8_t (&af)[4][2], bf16x8_t (&bfr)[2][2],
                                       f32x4_t (&acc)[8][4]) {
  __builtin_amdgcn_s_setprio(1);
#pragma unroll
  for (int mi = 0; mi < 4; ++mi)
#pragma unroll
    for (int ni = 0; ni < 2; ++ni) {
      f32x4_t& a = acc[MH * 4 + mi][NH * 2 + ni];
      a = __builtin_amdgcn_mfma_f32_16x16x32_bf16(af[mi][0], bfr[ni][0], a, 0, 0, 0);
      a = __builtin_amdgcn_mfma_f32_16x16x32_bf16(af[mi][1], bfr[ni][1], a, 0, 0, 0);
    }
  __builtin_amdgcn_s_setprio(0);
}

template <int OUT_BF16, int NWGX>
__global__ __launch_bounds__(512, 2) void gemm256p(const bf16* __restrict__ A,
                                                   const bf16* __restrict__ Bt,
                                                   const float* __restrict__ bias,
                                                   void* __restrict__ Cv) {
  constexpr int K = 1024;
  constexpr int N = NWGX * 256;
  constexpr int TT = NWGX / 4;     // output tiles per block (grid fixed at 256)
  constexpr int G = TT * 16;       // flattened K-steps
  constexpr int CPX = NWGX * 8;    // tiles per XCD chunk

  __shared__ __align__(16) bf16 lds[65536];  // 128 KiB
  const int tid = threadIdx.x;
  const int bx = blockIdx.x;

  const int wid = tid >> 6, lane = tid & 63;
  const int wr = wid >> 2, wc = wid & 3;
  const int lr = lane & 15, lg = lane >> 4;
  const int exr = (lr & 7) << 3;

  const int srow = tid >> 3;
  const int colg = ((((tid & 7) * 16) ^ ((srow & 7) << 4)) >> 1);
  const int browc0 = (srow >> 5) * 64 + (srow & 31);

  auto tileMN = [&](int tt, int& m0, int& n0) {
    int orig = bx + (tt << 8);
    int swz = (orig & 7) * CPX + (orig >> 3);
    m0 = (swz / NWGX) * 256;
    n0 = (swz % NWGX) * 256;
  };

  auto stageA = [&](int g, int h) {
    if (g >= G) return;
    int m0, n0; tileMN(g >> 4, m0, n0);
    const bf16* g0 = A + (size_t)(m0 + h * 64 + srow) * K + (g & 15) * 64 + colg;
    bf16* l = lds + (g & 1) * 32768 + h * 8192 + tid * 8;
    gl16(l, g0); gl16(l + 4096, g0 + (size_t)128 * K);
  };
  auto stageB = [&](int g, int h) {
    if (g >= G) return;
    int m0, n0; tileMN(g >> 4, m0, n0);
    const bf16* g0 = Bt + (size_t)(n0 + browc0 + h * 32) * K + (g & 15) * 64 + colg;
    bf16* l = lds + (g & 1) * 32768 + (2 + h) * 8192 + tid * 8;
    gl16(l, g0); gl16(l + 4096, g0 + (size_t)128 * K);
  };

  f32x4_t acc[8][4] = {};
  bf16x8_t af1[4][2], af2[4][2], b0[2][2], b1[2][2];

  // prologue: K-step 0 fully staged + {Ah0,Bh0}(1) in flight
  stageA(0, 0); stageB(0, 0); stageA(0, 1); stageB(0, 1);
  stageA(1, 0); stageB(1, 0);
  WAITVM(4);
  BARRIER();
  readA(lds, 0, wr, lr, lg, exr, af1);   // Ah0(0)
  readB(lds, 0, wc, lr, lg, exr, b0);    // Bh0(0)

  for (int g = 0; g < G; ++g) {
    const bf16* cb = lds + (g & 1) * 32768;
    const bf16* nb = lds + ((g & 1) ^ 1) * 32768;

    // phase 1: Q(0,0) = af1 x b0 ; prefetch b1 (Bh1 cur)
    stageA(g + 1, 1);
    BARRIER();
    readB(cb, 1, wc, lr, lg, exr, b1);
    SCHED0();
    mfma16<0, 0>(af1, b0, acc);

    // phase 2: Q(0,1) = af1 x b1 ; prefetch af2 (Ah1 cur)
    stageB(g + 1, 1);
    BARRIER();
    readA(cb, 1, wr, lr, lg, exr, af2);
    SCHED0();
    mfma16<0, 1>(af1, b1, acc);

    // phase 3: Q(1,0) = af2 x b0
    stageA(g + 2, 0);
    BARRIER();
    mfma16<1, 0>(af2, b0, acc);

    // phase 4: Q(1,1) = af2 x b1 ; prefetch af1,b0 from NEXT buffer
    stageB(g + 2, 0);
    if (g < G - 2) { WAITVM(4); } else { WAITVM(0); }
    BARRIER();
    if (g < G - 1) {
      readA(nb, 0, wr, lr, lg, exr, af1);
      readB(nb, 0, wc, lr, lg, exr, b0);
      SCHED0();
    }
    mfma16<1, 1>(af2, b1, acc);

    if ((g & 15) == 15) {
      BARRIER();  // keep dump stores out of the last phase's read window
      // dump finished tile; n innermost so each 64B C-line completes back-to-back
      int m0, n0; tileMN(g >> 4, m0, n0);
      float bv[4];
#pragma unroll
      for (int n = 0; n < 4; ++n) bv[n] = bias[n0 + wc * 64 + n * 16 + lr];
#pragma unroll
      for (int m = 0; m < 8; ++m) {
        int row = m0 + wr * 128 + m * 16 + lg * 4;
#pragma unroll
        for (int j = 0; j < 4; ++j) {
#pragma unroll
          for (int n = 0; n < 4; ++n) {
            int col = n0 + wc * 64 + n * 16 + lr;
            float v = acc[m][n][j] + bv[n];
            if (OUT_BF16)
              ((bf16*)Cv)[(size_t)(row + j) * N + col] = __float2bfloat16(v);
            else
              ((float*)Cv)[(size_t)(row + j) * N + col] = v;
            acc[m][n][j] = 0.f;
          }
        }
      }
    }
  }
}

// ---------------------------------------------------------------- per-token head-mixing attention (MFMA)
// qkv[t][0:1024]=q, [1024:2048]=k, [2048:3072]=v ; head layout idx = h*64+d
// logits[qh][kh] = 0.125 * dot(q[qh], k[kh]); softmax over kh; out[qh][d] = sum_kh p*v[kh][d]
#define PSTR 48
__global__ __launch_bounds__(256) void attn_tok(const bf16* __restrict__ qkv,
                                                bf16* __restrict__ out) {
  __shared__ __align__(16) bf16 vs[4][1024];
  __shared__ __align__(16) bf16 ps[4][16 * PSTR];
  const int w = threadIdx.x >> 6, l = threadIdx.x & 63;
  const int t = blockIdx.x * 4 + w;
  const int lr = l & 15, lg = l >> 4;
  const bf16* base = qkv + (size_t)t * 3072;

  bf16x8_t v0 = *(const bf16x8_t*)(base + 2048 + l * 16);
  bf16x8_t v1 = *(const bf16x8_t*)(base + 2048 + l * 16 + 8);
  *(bf16x8_t*)(&vs[w][l * 16]) = v0;
  *(bf16x8_t*)(&vs[w][l * 16 + 8]) = v1;

  *(unsigned long long*)(&ps[w][(l >> 2) * PSTR + 16 + (l & 3) * 4]) = 0ULL;

  const bf16* qp = base + lr * 64 + lg * 8;
  const bf16* kp = base + 1024 + lr * 64 + lg * 8;
  bf16x8_t qa0 = *(const bf16x8_t*)qp;
  bf16x8_t ka0 = *(const bf16x8_t*)kp;
  bf16x8_t qa1 = *(const bf16x8_t*)(qp + 32);
  bf16x8_t ka1 = *(const bf16x8_t*)(kp + 32);
  f32x4_t s = {};
  s = __builtin_amdgcn_mfma_f32_16x16x32_bf16(qa0, ka0, s, 0, 0, 0);
  s = __builtin_amdgcn_mfma_f32_16x16x32_bf16(qa1, ka1, s, 0, 0, 0);

#pragma unroll
  for (int j = 0; j < 4; ++j) {
    float x = s[j] * 0.125f;
    float mx = x;
#pragma unroll
    for (int off = 8; off; off >>= 1) mx = fmaxf(mx, __shfl_xor(mx, off, 16));
    float e = __expf(x - mx);
    float sum = e;
#pragma unroll
    for (int off = 8; off; off >>= 1) sum += __shfl_xor(sum, off, 16);
    ps[w][(lg * 4 + j) * PSTR + lr] = __float2bfloat16(e / sum);
  }

  bf16x8_t pf = *(const bf16x8_t*)(&ps[w][lr * PSTR + lg * 8]);
  bf16x8_t vf[4] = {};
  if (l < 32) {
#pragma unroll
    for (int c = 0; c < 4; ++c)
#pragma unroll
      for (int j = 0; j < 8; ++j)
        vf[c][j] = (__bf16)vs[w][(lg * 8 + j) * 64 + c * 16 + lr];
  }
  f32x4_t o[4] = {};
#pragma unroll
  for (int c = 0; c < 4; ++c)
    o[c] = __builtin_amdgcn_mfma_f32_16x16x32_bf16(pf, vf[c], o[c], 0, 0, 0);

  bf16* ob = out + (size_t)t * 1024;
#pragma unroll
  for (int c = 0; c < 4; ++c)
#pragma unroll
    for (int j = 0; j < 4; ++j)
      ob[(lg * 4 + j) * 64 + c * 16 + lr] = __float2bfloat16(o[c][j]);
}

// ---------------------------------------------------------------- launch
extern "C" void kernel_launch(void* const* d_in, const int* in_sizes, int n_in,
                              void* d_out, int out_size, void* d_ws, size_t ws_size,
                              hipStream_t stream) {
  const float* x    = (const float*)d_in[0];  // [16384,1024]
  const float* Wqkv = (const float*)d_in[1];  // [1024,3072]
  const float* bqkv = (const float*)d_in[2];  // [3072]
  const float* Wout = (const float*)d_in[3];  // [1024,1024]
  const float* bout = (const float*)d_in[4];  // [1024]
  float* y = (float*)d_out;                   // [16384,1024]

  const int T = 16384, HD = 1024, N1 = 3072;

  char* ws = (char*)d_ws;
  size_t off = 0;
  bf16* xb  = (bf16*)(ws + off); off += (size_t)T * HD * 2;
  bf16* w1t = (bf16*)(ws + off); off += (size_t)N1 * HD * 2;
  bf16* w2t = (bf16*)(ws + off); off += (size_t)HD * HD * 2;
  bf16* qkv = (bf16*)(ws + off); off += (size_t)T * N1 * 2;
  if (ws_size < off) return;
  bf16* ao = xb;  // xb dead after GEMM1; reuse as attention output

  prep_fused<<<16384 + 3072 + 1024, 256, 0, stream>>>(x, Wqkv, Wout, xb, w1t, w2t);
  gemm256p<1, 12><<<256, 512, 0, stream>>>(xb, w1t, bqkv, qkv);
  attn_tok<<<T / 4, 256, 0, stream>>>(qkv, ao);
  gemm256p<0, 4><<<256, 512, 0, stream>>>(ao, w2t, bout, y);
}